// Round 8
// baseline (718.453 us; speedup 1.0000x reference)
//
#include <hip/hip_runtime.h>
#include <hip/hip_bf16.h>
#include <math.h>

typedef __bf16 bf16;
typedef __bf16 bf16x4 __attribute__((ext_vector_type(4)));
typedef __bf16 bf16x8 __attribute__((ext_vector_type(8)));
typedef float  f32x4  __attribute__((ext_vector_type(4)));

#define HD 512
#define NB 128
#define NS 512
#define MS (NB*NS)   // 65536

__device__ __forceinline__ float sigmoidf_(float x){ return 1.0f/(1.0f+expf(-x)); }

__device__ __forceinline__ float fast_tanh(float x){
    float ax = fabsf(x);
    float e  = __expf(-2.0f*ax);
    float t  = (1.0f - e) * __builtin_amdgcn_rcpf(1.0f + e);
    return copysignf(t, x);
}

// ---- K0: W1 (512x512 fp32 [o][h]) -> bf16 MFMA B-fragment order.
// Frag F = (g*16 + ki)*4 + fnl  (g=col-group 0..7 (64 cols), ki=0..15, fnl=0..3).
// Lane l of F holds W1[(g*4+fnl)*16 + (l&15)][ki*32 + (l>>4)*8 + j] at W1s[F*512 + l*8 + j].
__global__ __launch_bounds__(256) void cvt_w1_frag(const float* __restrict__ W1, bf16* __restrict__ W1s){
    int F = blockIdx.x*4 + (threadIdx.x>>6);
    int l = threadIdx.x & 63;
    int fnl = F & 3, ki = (F>>2) & 15, g = F>>6;
    int row = (g*4 + fnl)*16 + (l & 15);
    int kk  = ki*32 + (l >> 4)*8;
    const f32x4* gp = (const f32x4*)&W1[(size_t)row*512 + kk];
    f32x4 v0 = gp[0], v1 = gp[1];
    bf16x8 hv;
    #pragma unroll
    for (int j=0;j<4;++j){ hv[j]=(bf16)v0[j]; hv[4+j]=(bf16)v1[j]; }
    *(bf16x8*)&W1s[(size_t)F*512 + (size_t)l*8] = hv;
}

// ---- K1/K2: small GEMM, 3-term bf16 split, split-K, transposed output ----
__global__ __launch_bounds__(256) void gemm_split(
    const float* __restrict__ A1, const float* __restrict__ A2,
    const float* __restrict__ B1, const float* __restrict__ B2,
    const float* __restrict__ bias1, const float* __restrict__ bias2,
    float* __restrict__ C, int N, int ksize, int ldct)
{
    __shared__ bf16 Ah[64][32], Al[64][32], Bh[64][32], Bl[64][32];
    int tid = threadIdx.x;
    int bm = blockIdx.x, bn = blockIdx.y, ks = blockIdx.z;
    int kfrom = ks*ksize, kend = kfrom + ksize;
    float* Cz = C + (size_t)ks * N * ldct;
    int w = tid>>6, l = tid&63;
    int wm = w>>1, wn = w&1;
    f32x4 acc[2][2] = {};
    for (int k0 = kfrom; k0 < kend; k0 += 32){
        const float* Ap = (k0 < 512) ? A1 : A2;
        const float* Bp = (k0 < 512) ? B1 : B2;
        int kk = k0 & 511;
        __syncthreads();
        #pragma unroll
        for (int q = 0; q < 2; ++q){
            int id  = q*256 + tid;
            int row = id >> 3, c4 = (id & 7)*4;
            f32x4 va = *(const f32x4*)&Ap[(size_t)(bm*64+row)*512 + kk + c4];
            f32x4 vb = *(const f32x4*)&Bp[(size_t)(bn*64+row)*512 + kk + c4];
            bf16x4 vah, val_, vbh, vbl;
            #pragma unroll
            for (int j=0;j<4;++j){
                bf16 ha = (bf16)va[j]; vah[j]=ha; val_[j]=(bf16)(va[j]-(float)ha);
                bf16 hb = (bf16)vb[j]; vbh[j]=hb; vbl[j]=(bf16)(vb[j]-(float)hb);
            }
            *(bf16x4*)&Ah[row][c4] = vah;  *(bf16x4*)&Al[row][c4] = val_;
            *(bf16x4*)&Bh[row][c4] = vbh;  *(bf16x4*)&Bl[row][c4] = vbl;
        }
        __syncthreads();
        int koff = (l>>4)*8;
        int ar = wm*32 + (l&15);
        int br = wn*32 + (l&15);
        bf16x8 ah[2], al[2], bh[2], bl[2];
        ah[0]=*(const bf16x8*)&Ah[ar][koff];    ah[1]=*(const bf16x8*)&Ah[ar+16][koff];
        al[0]=*(const bf16x8*)&Al[ar][koff];    al[1]=*(const bf16x8*)&Al[ar+16][koff];
        bh[0]=*(const bf16x8*)&Bh[br][koff];    bh[1]=*(const bf16x8*)&Bh[br+16][koff];
        bl[0]=*(const bf16x8*)&Bl[br][koff];    bl[1]=*(const bf16x8*)&Bl[br+16][koff];
        #pragma unroll
        for (int fm=0; fm<2; ++fm)
        #pragma unroll
        for (int fn=0; fn<2; ++fn){
            acc[fm][fn] = __builtin_amdgcn_mfma_f32_16x16x32_bf16(ah[fm], bh[fn], acc[fm][fn],0,0,0);
            acc[fm][fn] = __builtin_amdgcn_mfma_f32_16x16x32_bf16(ah[fm], bl[fn], acc[fm][fn],0,0,0);
            acc[fm][fn] = __builtin_amdgcn_mfma_f32_16x16x32_bf16(al[fm], bh[fn], acc[fm][fn],0,0,0);
        }
    }
    #pragma unroll
    for (int fm=0; fm<2; ++fm)
    #pragma unroll
    for (int fn=0; fn<2; ++fn){
        #pragma unroll
        for (int r=0; r<4; ++r){
            int m = bm*64 + wm*32 + fm*16 + ((l>>4)<<2) + r;
            int n = bn*64 + wn*32 + fn*16 + (l&15);
            float v = acc[fm][fn][r];
            if (ks == 0){
                if (bias1) v += bias1[m];
                if (bias2) v += bias2[m];
            }
            Cz[(size_t)n*ldct + m] = v;
        }
    }
}

// ---- K1b: LSTM pointwise (sums split-K partials) + zeroes a10 for atomics ----
__global__ __launch_bounds__(256) void lstm_pointwise(
    const float* __restrict__ gatesT, const float* __restrict__ c_in,
    float* __restrict__ h_out, float* __restrict__ c_out, float* __restrict__ a10)
{
    int t = blockIdx.x*256 + threadIdx.x;
    int b = t >> 9, hh = t & 511;
    const float* gp = gatesT + (size_t)b*2048 + hh;
    float gi=0.f, gf=0.f, gg=0.f, go=0.f;
    #pragma unroll
    for (int ks=0; ks<4; ++ks){
        const float* p = gp + (size_t)ks*262144;
        gi += p[0]; gf += p[512]; gg += p[1024]; go += p[1536];
    }
    float i = sigmoidf_(gi), f = sigmoidf_(gf), g = tanhf(gg), o = sigmoidf_(go);
    float cn = f*c_in[t] + i*g;
    float hn = o*tanhf(cn);
    h_out[t] = hn;  c_out[t] = cn;
    a10[t] = 0.f;
}

// ---- K3 v2: barrier-free, LDS-free K-loop, max occupancy.
// Block = 256 thr (4 waves); wave = 64 rows x 64 cols; grid = (M/64, 2 col-halves).
// A: global->reg fp32, 1 step ahead, inline cvt.  B: frag-ordered L2, 2 steps ahead.
// 8 blocks/CU co-resident (launch_bounds(256,8)) -> TLP hides all latency.
// Partial sums over the col-half -> atomicAdd into a10 (zeroed by lstm_pointwise).
__global__ __launch_bounds__(256,8) void attn_main(
    const float* __restrict__ enc, const bf16* __restrict__ W1s,
    const float* __restrict__ w2hp, const float* __restrict__ Vv,
    float* __restrict__ a10)
{
    __shared__ float w2h_s[512];
    __shared__ float V_s[512];
    __shared__ float red[64][4];
    const int tid = threadIdx.x, w = tid>>6, l = tid&63;
    const int lr = l & 15, lk = l >> 4;
    const int m0 = blockIdx.x * 64;
    const int g  = blockIdx.y*4 + w;          // col group (64 cols)
    const int bidx = blockIdx.x >> 3;         // batch index
    // stage w2h (sum 2 split-K partials) + V; consumed only after the K-loop barrier
    w2h_s[tid]     = w2hp[(size_t)bidx*512 + tid]       + w2hp[(size_t)65536 + bidx*512 + tid];
    w2h_s[tid+256] = w2hp[(size_t)bidx*512 + tid + 256] + w2hp[(size_t)65536 + bidx*512 + tid + 256];
    V_s[tid] = Vv[tid];  V_s[tid+256] = Vv[tid+256];

    const float* Abase = enc + (size_t)(m0 + lr)*512 + lk*8;   // + fm*16*512 + ki*32
    const bf16*  Bbase = W1s + (size_t)g*32768 + (size_t)l*8;  // + fnl*512 + ki*2048

    f32x4 acc[4][4] = {};
    f32x4 rE[4][2], rO[4][2];
    bf16x8 bE[4], bO[4];

    #pragma unroll
    for (int fm=0; fm<4; ++fm){
        const f32x4* p = (const f32x4*)(Abase + fm*8192);
        rE[fm][0] = p[0]; rE[fm][1] = p[1];
    }
    #pragma unroll
    for (int fn=0; fn<4; ++fn) bE[fn] = *(const bf16x8*)(Bbase + fn*512);
    #pragma unroll
    for (int fn=0; fn<4; ++fn) bO[fn] = *(const bf16x8*)(Bbase + fn*512 + 2048);

    #pragma unroll
    for (int kp=0; kp<8; ++kp){
        const int ke = 2*kp, ko = 2*kp+1;
        // issue A(ko)
        #pragma unroll
        for (int fm=0; fm<4; ++fm){
            const f32x4* p = (const f32x4*)(Abase + fm*8192 + ko*32);
            rO[fm][0] = p[0]; rO[fm][1] = p[1];
        }
        // even step: pref B(ke+2), cvt A(ke), MFMA
        {
            bf16x8 nb[4];
            #pragma unroll
            for (int fn=0; fn<4; ++fn) nb[fn] = *(const bf16x8*)(Bbase + fn*512 + (size_t)((ke+2)&15)*2048);
            bf16x8 af[4];
            #pragma unroll
            for (int fm=0; fm<4; ++fm){
                #pragma unroll
                for (int j=0;j<4;++j){ af[fm][j]=(bf16)rE[fm][0][j]; af[fm][4+j]=(bf16)rE[fm][1][j]; }
            }
            #pragma unroll
            for (int fm=0; fm<4; ++fm)
            #pragma unroll
            for (int fn=0; fn<4; ++fn)
                acc[fm][fn] = __builtin_amdgcn_mfma_f32_16x16x32_bf16(af[fm], bE[fn], acc[fm][fn],0,0,0);
            #pragma unroll
            for (int fn=0; fn<4; ++fn) bE[fn] = nb[fn];
        }
        // issue A(ke+2)
        if (kp < 7){
            #pragma unroll
            for (int fm=0; fm<4; ++fm){
                const f32x4* p = (const f32x4*)(Abase + fm*8192 + (ke+2)*32);
                rE[fm][0] = p[0]; rE[fm][1] = p[1];
            }
        }
        // odd step: pref B(ko+2), cvt A(ko), MFMA
        {
            bf16x8 nb[4];
            #pragma unroll
            for (int fn=0; fn<4; ++fn) nb[fn] = *(const bf16x8*)(Bbase + fn*512 + (size_t)((ko+2)&15)*2048);
            bf16x8 af[4];
            #pragma unroll
            for (int fm=0; fm<4; ++fm){
                #pragma unroll
                for (int j=0;j<4;++j){ af[fm][j]=(bf16)rO[fm][0][j]; af[fm][4+j]=(bf16)rO[fm][1][j]; }
            }
            #pragma unroll
            for (int fm=0; fm<4; ++fm)
            #pragma unroll
            for (int fn=0; fn<4; ++fn)
                acc[fm][fn] = __builtin_amdgcn_mfma_f32_16x16x32_bf16(af[fm], bO[fn], acc[fm][fn],0,0,0);
            #pragma unroll
            for (int fn=0; fn<4; ++fn) bO[fn] = nb[fn];
        }
    }

    __syncthreads();   // w2h_s / V_s visibility (staged at kernel start)

    // epilogue: partial over this col-half: sum_o tanh(C + w2h[o]) * V[o]
    #pragma unroll
    for (int fm=0; fm<4; ++fm){
        float asum[4] = {0.f,0.f,0.f,0.f};
        #pragma unroll
        for (int fn=0; fn<4; ++fn){
            int o = g*64 + fn*16 + lr;
            float wv = w2h_s[o], vv = V_s[o];
            #pragma unroll
            for (int r=0;r<4;++r)
                asum[r] += fast_tanh(acc[fm][fn][r] + wv) * vv;
        }
        #pragma unroll
        for (int off=1; off<16; off<<=1){
            #pragma unroll
            for (int r=0;r<4;++r) asum[r] += __shfl_xor(asum[r], off, 64);
        }
        if (lr == 0){
            #pragma unroll
            for (int r=0;r<4;++r) red[fm*16 + lk*4 + r][w] = asum[r];
        }
    }
    __syncthreads();
    if (tid < 64){
        float a = red[tid][0] + red[tid][1] + red[tid][2] + red[tid][3];
        atomicAdd(&a10[m0 + tid], a);
    }
}

// ---- K4: masked softmax over S=512 per row (applies the 10*tanh here,
// since a10 holds the raw sum assembled from two atomic partials) ----
__global__ __launch_bounds__(512) void softmax_k(
    const float* __restrict__ a10, const float* __restrict__ mask,
    float* __restrict__ out)
{
    int b = blockIdx.x, tid = threadIdx.x;
    __shared__ float sred[8];
    float v = 10.0f*fast_tanh(a10[(size_t)b*512 + tid]) + logf(mask[(size_t)b*512 + tid]);
    float m = v;
    #pragma unroll
    for (int off=1; off<64; off<<=1) m = fmaxf(m, __shfl_xor(m, off, 64));
    if ((tid&63)==0) sred[tid>>6] = m;
    __syncthreads();
    float mt = sred[0];
    #pragma unroll
    for (int i=1;i<8;++i) mt = fmaxf(mt, sred[i]);
    float e = expf(v - mt);
    float s = e;
    #pragma unroll
    for (int off=1; off<64; off<<=1) s += __shfl_xor(s, off, 64);
    __syncthreads();
    if ((tid&63)==0) sred[tid>>6] = s;
    __syncthreads();
    float st = 0.f;
    #pragma unroll
    for (int i=0;i<8;++i) st += sred[i];
    out[(size_t)b*512 + tid] = e / st;
}

extern "C" void kernel_launch(void* const* d_in, const int* in_sizes, int n_in,
                              void* d_out, int out_size, void* d_ws, size_t ws_size,
                              hipStream_t stream)
{
    const float* x    = (const float*)d_in[0];
    const float* h    = (const float*)d_in[1];
    const float* c    = (const float*)d_in[2];
    const float* enc  = (const float*)d_in[3];
    const float* mask = (const float*)d_in[4];
    const float* W1   = (const float*)d_in[5];
    const float* W2   = (const float*)d_in[6];
    const float* b2   = (const float*)d_in[7];
    const float* V    = (const float*)d_in[8];
    const float* Wih  = (const float*)d_in[9];
    const float* Whh  = (const float*)d_in[10];
    const float* bih  = (const float*)d_in[11];
    const float* bhh  = (const float*)d_in[12];

    float* out_policy = (float*)d_out;
    float* out_h = out_policy + MS;
    float* out_c = out_policy + 2*MS;

    float* ws_f   = (float*)d_ws;
    float* gatesT = ws_f;                    // 4 x 262144 f32 (split-K partials, [b][j])
    float* w2hp   = ws_f + 1048576;          // 2 x  65536 f32 (split-K partials, [b][o])
    float* a10    = ws_f + 1179648;          //      65536 f32 (atomic accumulator)
    bf16*  W1s    = (bf16*)(ws_f + 1245184); //     262144 bf16 (fragment-ordered)

    cvt_w1_frag<<<128, 256, 0, stream>>>(W1, W1s);
    gemm_split<<<dim3(32,2,4), 256, 0, stream>>>(Wih, Whh, x, h, bih, bhh, gatesT, 128, 256, 2048);
    lstm_pointwise<<<256, 256, 0, stream>>>(gatesT, c, out_h, out_c, a10);
    gemm_split<<<dim3(8,2,2), 256, 0, stream>>>(W2, nullptr, out_h, nullptr, b2, nullptr, w2hp, 128, 256, 512);
    attn_main<<<dim3(1024,2), 256, 0, stream>>>(enc, W1s, w2hp, V, a10);
    softmax_k<<<128, 512, 0, stream>>>(a10, mask, out_policy);
}

// Round 9
// 295.298 us; speedup vs baseline: 2.4330x; 2.4330x over previous
//
#include <hip/hip_runtime.h>
#include <hip/hip_bf16.h>
#include <math.h>

typedef __bf16 bf16;
typedef __bf16 bf16x4 __attribute__((ext_vector_type(4)));
typedef __bf16 bf16x8 __attribute__((ext_vector_type(8)));
typedef float  f32x4  __attribute__((ext_vector_type(4)));

#define HD 512
#define NB 128
#define NS 512
#define MS (NB*NS)   // 65536

__device__ __forceinline__ float sigmoidf_(float x){ return 1.0f/(1.0f+expf(-x)); }

__device__ __forceinline__ float fast_tanh(float x){
    float ax = fabsf(x);
    float e  = __expf(-2.0f*ax);
    float t  = (1.0f - e) * __builtin_amdgcn_rcpf(1.0f + e);
    return copysignf(t, x);
}

// ---- K0: W1 (512x512 fp32 [o][h]) -> bf16 MFMA B-fragment order.
// Frag F = (g*16 + ki)*4 + fnl  (g=64-col group 0..7, ki=0..15, fnl=0..3).
// Lane l of F holds W1[(g*4+fnl)*16 + (l&15)][ki*32 + (l>>4)*8 + j] at W1s[F*512 + l*8 + j].
__global__ __launch_bounds__(256) void cvt_w1_frag(const float* __restrict__ W1, bf16* __restrict__ W1s){
    int F = blockIdx.x*4 + (threadIdx.x>>6);
    int l = threadIdx.x & 63;
    int fnl = F & 3, ki = (F>>2) & 15, g = F>>6;
    int row = (g*4 + fnl)*16 + (l & 15);
    int kk  = ki*32 + (l >> 4)*8;
    const f32x4* gp = (const f32x4*)&W1[(size_t)row*512 + kk];
    f32x4 v0 = gp[0], v1 = gp[1];
    bf16x8 hv;
    #pragma unroll
    for (int j=0;j<4;++j){ hv[j]=(bf16)v0[j]; hv[4+j]=(bf16)v1[j]; }
    *(bf16x8*)&W1s[(size_t)F*512 + (size_t)l*8] = hv;
}

// ---- K1/K2: small GEMM, 3-term bf16 split, split-K, transposed output ----
__global__ __launch_bounds__(256) void gemm_split(
    const float* __restrict__ A1, const float* __restrict__ A2,
    const float* __restrict__ B1, const float* __restrict__ B2,
    const float* __restrict__ bias1, const float* __restrict__ bias2,
    float* __restrict__ C, int N, int ksize, int ldct)
{
    __shared__ bf16 Ah[64][32], Al[64][32], Bh[64][32], Bl[64][32];
    int tid = threadIdx.x;
    int bm = blockIdx.x, bn = blockIdx.y, ks = blockIdx.z;
    int kfrom = ks*ksize, kend = kfrom + ksize;
    float* Cz = C + (size_t)ks * N * ldct;
    int w = tid>>6, l = tid&63;
    int wm = w>>1, wn = w&1;
    f32x4 acc[2][2] = {};
    for (int k0 = kfrom; k0 < kend; k0 += 32){
        const float* Ap = (k0 < 512) ? A1 : A2;
        const float* Bp = (k0 < 512) ? B1 : B2;
        int kk = k0 & 511;
        __syncthreads();
        #pragma unroll
        for (int q = 0; q < 2; ++q){
            int id  = q*256 + tid;
            int row = id >> 3, c4 = (id & 7)*4;
            f32x4 va = *(const f32x4*)&Ap[(size_t)(bm*64+row)*512 + kk + c4];
            f32x4 vb = *(const f32x4*)&Bp[(size_t)(bn*64+row)*512 + kk + c4];
            bf16x4 vah, val_, vbh, vbl;
            #pragma unroll
            for (int j=0;j<4;++j){
                bf16 ha = (bf16)va[j]; vah[j]=ha; val_[j]=(bf16)(va[j]-(float)ha);
                bf16 hb = (bf16)vb[j]; vbh[j]=hb; vbl[j]=(bf16)(vb[j]-(float)hb);
            }
            *(bf16x4*)&Ah[row][c4] = vah;  *(bf16x4*)&Al[row][c4] = val_;
            *(bf16x4*)&Bh[row][c4] = vbh;  *(bf16x4*)&Bl[row][c4] = vbl;
        }
        __syncthreads();
        int koff = (l>>4)*8;
        int ar = wm*32 + (l&15);
        int br = wn*32 + (l&15);
        bf16x8 ah[2], al[2], bh[2], bl[2];
        ah[0]=*(const bf16x8*)&Ah[ar][koff];    ah[1]=*(const bf16x8*)&Ah[ar+16][koff];
        al[0]=*(const bf16x8*)&Al[ar][koff];    al[1]=*(const bf16x8*)&Al[ar+16][koff];
        bh[0]=*(const bf16x8*)&Bh[br][koff];    bh[1]=*(const bf16x8*)&Bh[br+16][koff];
        bl[0]=*(const bf16x8*)&Bl[br][koff];    bl[1]=*(const bf16x8*)&Bl[br+16][koff];
        #pragma unroll
        for (int fm=0; fm<2; ++fm)
        #pragma unroll
        for (int fn=0; fn<2; ++fn){
            acc[fm][fn] = __builtin_amdgcn_mfma_f32_16x16x32_bf16(ah[fm], bh[fn], acc[fm][fn],0,0,0);
            acc[fm][fn] = __builtin_amdgcn_mfma_f32_16x16x32_bf16(ah[fm], bl[fn], acc[fm][fn],0,0,0);
            acc[fm][fn] = __builtin_amdgcn_mfma_f32_16x16x32_bf16(al[fm], bh[fn], acc[fm][fn],0,0,0);
        }
    }
    #pragma unroll
    for (int fm=0; fm<2; ++fm)
    #pragma unroll
    for (int fn=0; fn<2; ++fn){
        #pragma unroll
        for (int r=0; r<4; ++r){
            int m = bm*64 + wm*32 + fm*16 + ((l>>4)<<2) + r;
            int n = bn*64 + wn*32 + fn*16 + (l&15);
            float v = acc[fm][fn][r];
            if (ks == 0){
                if (bias1) v += bias1[m];
                if (bias2) v += bias2[m];
            }
            Cz[(size_t)n*ldct + m] = v;
        }
    }
}

// ---- K1b: LSTM pointwise (sums split-K partials) + zeroes a10 for atomics ----
__global__ __launch_bounds__(256) void lstm_pointwise(
    const float* __restrict__ gatesT, const float* __restrict__ c_in,
    float* __restrict__ h_out, float* __restrict__ c_out, float* __restrict__ a10)
{
    int t = blockIdx.x*256 + threadIdx.x;
    int b = t >> 9, hh = t & 511;
    const float* gp = gatesT + (size_t)b*2048 + hh;
    float gi=0.f, gf=0.f, gg=0.f, go=0.f;
    #pragma unroll
    for (int ks=0; ks<4; ++ks){
        const float* p = gp + (size_t)ks*262144;
        gi += p[0]; gf += p[512]; gg += p[1024]; go += p[1536];
    }
    float i = sigmoidf_(gi), f = sigmoidf_(gf), g = tanhf(gg), o = sigmoidf_(go);
    float cn = f*c_in[t] + i*g;
    float hn = o*tanhf(cn);
    h_out[t] = hn;  c_out[t] = cn;
    a10[t] = 0.f;
}

// ---- K3 v3: barrier-free, LDS-free K-loop; register budget sized for
// 3 blocks/CU (12 waves/CU) with NO spills.  Block = 256 thr (4 waves);
// wave = 64 rows x 32 cols; grid = (1024 rowblocks, 4 col-quarters).
// A: global->reg fp32 (1 step ahead, inline cvt; L3-resident re-reads).
// B: frag-ordered W1s from L2, 2 K-steps ahead.  ~150 VGPR/lane.
__global__ __launch_bounds__(256,3) void attn_main(
    const float* __restrict__ enc, const bf16* __restrict__ W1s,
    const float* __restrict__ w2hp, const float* __restrict__ Vv,
    float* __restrict__ a10)
{
    __shared__ float w2h_s[512];
    __shared__ float V_s[512];
    __shared__ float red[64][4];
    const int tid = threadIdx.x, w = tid>>6, l = tid&63;
    const int lr = l & 15, lk = l >> 4;
    const int m0 = blockIdx.x * 64;
    const int g  = blockIdx.y*4 + w;          // 32-col group id (0..15)
    const int bidx = blockIdx.x >> 3;         // batch index
    w2h_s[tid]     = w2hp[(size_t)bidx*512 + tid]       + w2hp[(size_t)65536 + bidx*512 + tid];
    w2h_s[tid+256] = w2hp[(size_t)bidx*512 + tid + 256] + w2hp[(size_t)65536 + bidx*512 + tid + 256];
    V_s[tid] = Vv[tid];  V_s[tid+256] = Vv[tid+256];

    const float* Abase = enc + (size_t)(m0 + lr)*512 + lk*8;              // + fm*16*512 + ki*32
    const bf16*  Bbase = W1s + (size_t)(g>>1)*32768 + (size_t)(g&1)*1024  // 64-col group + half
                             + (size_t)l*8;                               // + fn*512 + ki*2048

    f32x4 acc[4][2] = {};
    f32x4 rE[4][2], rO[4][2];
    bf16x8 bE[2], bO[2];

    #pragma unroll
    for (int fm=0; fm<4; ++fm){
        const f32x4* p = (const f32x4*)(Abase + fm*8192);
        rE[fm][0] = p[0]; rE[fm][1] = p[1];
    }
    #pragma unroll
    for (int fn=0; fn<2; ++fn) bE[fn] = *(const bf16x8*)(Bbase + fn*512);
    #pragma unroll
    for (int fn=0; fn<2; ++fn) bO[fn] = *(const bf16x8*)(Bbase + fn*512 + 2048);

    #pragma unroll
    for (int kp=0; kp<8; ++kp){
        const int ke = 2*kp, ko = 2*kp+1;
        // issue A(ko)
        #pragma unroll
        for (int fm=0; fm<4; ++fm){
            const f32x4* p = (const f32x4*)(Abase + fm*8192 + ko*32);
            rO[fm][0] = p[0]; rO[fm][1] = p[1];
        }
        // even: pref B(ke+2), cvt A(ke), MFMA
        {
            bf16x8 nb[2];
            #pragma unroll
            for (int fn=0; fn<2; ++fn) nb[fn] = *(const bf16x8*)(Bbase + fn*512 + (size_t)((ke+2)&15)*2048);
            bf16x8 af[4];
            #pragma unroll
            for (int fm=0; fm<4; ++fm){
                #pragma unroll
                for (int j=0;j<4;++j){ af[fm][j]=(bf16)rE[fm][0][j]; af[fm][4+j]=(bf16)rE[fm][1][j]; }
            }
            #pragma unroll
            for (int fm=0; fm<4; ++fm)
            #pragma unroll
            for (int fn=0; fn<2; ++fn)
                acc[fm][fn] = __builtin_amdgcn_mfma_f32_16x16x32_bf16(af[fm], bE[fn], acc[fm][fn],0,0,0);
            #pragma unroll
            for (int fn=0; fn<2; ++fn) bE[fn] = nb[fn];
        }
        // issue A(ke+2)
        if (kp < 7){
            #pragma unroll
            for (int fm=0; fm<4; ++fm){
                const f32x4* p = (const f32x4*)(Abase + fm*8192 + (ke+2)*32);
                rE[fm][0] = p[0]; rE[fm][1] = p[1];
            }
        }
        // odd: pref B(ko+2), cvt A(ko), MFMA
        {
            bf16x8 nb[2];
            #pragma unroll
            for (int fn=0; fn<2; ++fn) nb[fn] = *(const bf16x8*)(Bbase + fn*512 + (size_t)((ko+2)&15)*2048);
            bf16x8 af[4];
            #pragma unroll
            for (int fm=0; fm<4; ++fm){
                #pragma unroll
                for (int j=0;j<4;++j){ af[fm][j]=(bf16)rO[fm][0][j]; af[fm][4+j]=(bf16)rO[fm][1][j]; }
            }
            #pragma unroll
            for (int fm=0; fm<4; ++fm)
            #pragma unroll
            for (int fn=0; fn<2; ++fn)
                acc[fm][fn] = __builtin_amdgcn_mfma_f32_16x16x32_bf16(af[fm], bO[fn], acc[fm][fn],0,0,0);
            #pragma unroll
            for (int fn=0; fn<2; ++fn) bO[fn] = nb[fn];
        }
    }

    __syncthreads();   // w2h_s / V_s visibility

    // epilogue: partial over this 32-col group: sum_o tanh(C + w2h[o]) * V[o]
    #pragma unroll
    for (int fm=0; fm<4; ++fm){
        float asum[4] = {0.f,0.f,0.f,0.f};
        #pragma unroll
        for (int fn=0; fn<2; ++fn){
            int o = g*32 + fn*16 + lr;
            float wv = w2h_s[o], vv = V_s[o];
            #pragma unroll
            for (int r=0;r<4;++r)
                asum[r] += fast_tanh(acc[fm][fn][r] + wv) * vv;
        }
        #pragma unroll
        for (int off=1; off<16; off<<=1){
            #pragma unroll
            for (int r=0;r<4;++r) asum[r] += __shfl_xor(asum[r], off, 64);
        }
        if (lr == 0){
            #pragma unroll
            for (int r=0;r<4;++r) red[fm*16 + lk*4 + r][w] = asum[r];
        }
    }
    __syncthreads();
    if (tid < 64){
        float a = red[tid][0] + red[tid][1] + red[tid][2] + red[tid][3];
        atomicAdd(&a10[m0 + tid], a);
    }
}

// ---- K4: masked softmax over S=512 per row (applies 10*tanh to the
// atomically-assembled raw sum) ----
__global__ __launch_bounds__(512) void softmax_k(
    const float* __restrict__ a10, const float* __restrict__ mask,
    float* __restrict__ out)
{
    int b = blockIdx.x, tid = threadIdx.x;
    __shared__ float sred[8];
    float v = 10.0f*fast_tanh(a10[(size_t)b*512 + tid]) + logf(mask[(size_t)b*512 + tid]);
    float m = v;
    #pragma unroll
    for (int off=1; off<64; off<<=1) m = fmaxf(m, __shfl_xor(m, off, 64));
    if ((tid&63)==0) sred[tid>>6] = m;
    __syncthreads();
    float mt = sred[0];
    #pragma unroll
    for (int i=1;i<8;++i) mt = fmaxf(mt, sred[i]);
    float e = expf(v - mt);
    float s = e;
    #pragma unroll
    for (int off=1; off<64; off<<=1) s += __shfl_xor(s, off, 64);
    __syncthreads();
    if ((tid&63)==0) sred[tid>>6] = s;
    __syncthreads();
    float st = 0.f;
    #pragma unroll
    for (int i=0;i<8;++i) st += sred[i];
    out[(size_t)b*512 + tid] = e / st;
}

extern "C" void kernel_launch(void* const* d_in, const int* in_sizes, int n_in,
                              void* d_out, int out_size, void* d_ws, size_t ws_size,
                              hipStream_t stream)
{
    const float* x    = (const float*)d_in[0];
    const float* h    = (const float*)d_in[1];
    const float* c    = (const float*)d_in[2];
    const float* enc  = (const float*)d_in[3];
    const float* mask = (const float*)d_in[4];
    const float* W1   = (const float*)d_in[5];
    const float* W2   = (const float*)d_in[6];
    const float* b2   = (const float*)d_in[7];
    const float* V    = (const float*)d_in[8];
    const float* Wih  = (const float*)d_in[9];
    const float* Whh  = (const float*)d_in[10];
    const float* bih  = (const float*)d_in[11];
    const float* bhh  = (const float*)d_in[12];

    float* out_policy = (float*)d_out;
    float* out_h = out_policy + MS;
    float* out_c = out_policy + 2*MS;

    float* ws_f   = (float*)d_ws;
    float* gatesT = ws_f;                    // 4 x 262144 f32 (split-K partials, [b][j])
    float* w2hp   = ws_f + 1048576;          // 2 x  65536 f32 (split-K partials, [b][o])
    float* a10    = ws_f + 1179648;          //      65536 f32 (atomic accumulator)
    bf16*  W1s    = (bf16*)(ws_f + 1245184); //     262144 bf16 (fragment-ordered)

    cvt_w1_frag<<<128, 256, 0, stream>>>(W1, W1s);
    gemm_split<<<dim3(32,2,4), 256, 0, stream>>>(Wih, Whh, x, h, bih, bhh, gatesT, 128, 256, 2048);
    lstm_pointwise<<<256, 256, 0, stream>>>(gatesT, c, out_h, out_c, a10);
    gemm_split<<<dim3(8,2,2), 256, 0, stream>>>(W2, nullptr, out_h, nullptr, b2, nullptr, w2hp, 128, 256, 512);
    attn_main<<<dim3(1024,4), 256, 0, stream>>>(enc, W1s, w2hp, V, a10);
    softmax_k<<<128, 512, 0, stream>>>(a10, mask, out_policy);
}

// Round 10
// 107.137 us; speedup vs baseline: 6.7060x; 2.7563x over previous
//
#include <hip/hip_runtime.h>
#include <hip/hip_bf16.h>
#include <math.h>

typedef __bf16 bf16;
typedef __bf16 bf16x4 __attribute__((ext_vector_type(4)));
typedef __bf16 bf16x8 __attribute__((ext_vector_type(8)));
typedef float  f32x4  __attribute__((ext_vector_type(4)));

#define HD 512
#define NB 128
#define NS 512
#define MS (NB*NS)   // 65536

__device__ __forceinline__ float sigmoidf_(float x){ return 1.0f/(1.0f+expf(-x)); }

__device__ __forceinline__ float fast_tanh(float x){
    float ax = fabsf(x);
    float e  = __expf(-2.0f*ax);
    float t  = (1.0f - e) * __builtin_amdgcn_rcpf(1.0f + e);
    return copysignf(t, x);
}

// ---- K0: W1 (512x512 fp32 [o][h]) -> bf16 MFMA B-fragment order.
// Frag F = (g64*16 + ki)*4 + fnl ; lane l holds W1[(g64*4+fnl)*16+(l&15)][ki*32+(l>>4)*8+j]
// at W1s[F*512 + l*8 + j].
__global__ __launch_bounds__(256) void cvt_w1_frag(const float* __restrict__ W1, bf16* __restrict__ W1s){
    int F = blockIdx.x*4 + (threadIdx.x>>6);
    int l = threadIdx.x & 63;
    int fnl = F & 3, ki = (F>>2) & 15, g = F>>6;
    int row = (g*4 + fnl)*16 + (l & 15);
    int kk  = ki*32 + (l >> 4)*8;
    const f32x4* gp = (const f32x4*)&W1[(size_t)row*512 + kk];
    f32x4 v0 = gp[0], v1 = gp[1];
    bf16x8 hv;
    #pragma unroll
    for (int j=0;j<4;++j){ hv[j]=(bf16)v0[j]; hv[4+j]=(bf16)v1[j]; }
    *(bf16x8*)&W1s[(size_t)F*512 + (size_t)l*8] = hv;
}

// ---- K1/K2: small GEMM, 3-term bf16 split, split-K, transposed output ----
__global__ __launch_bounds__(256) void gemm_split(
    const float* __restrict__ A1, const float* __restrict__ A2,
    const float* __restrict__ B1, const float* __restrict__ B2,
    const float* __restrict__ bias1, const float* __restrict__ bias2,
    float* __restrict__ C, int N, int ksize, int ldct)
{
    __shared__ bf16 Ah[64][32], Al[64][32], Bh[64][32], Bl[64][32];
    int tid = threadIdx.x;
    int bm = blockIdx.x, bn = blockIdx.y, ks = blockIdx.z;
    int kfrom = ks*ksize, kend = kfrom + ksize;
    float* Cz = C + (size_t)ks * N * ldct;
    int w = tid>>6, l = tid&63;
    int wm = w>>1, wn = w&1;
    f32x4 acc[2][2] = {};
    for (int k0 = kfrom; k0 < kend; k0 += 32){
        const float* Ap = (k0 < 512) ? A1 : A2;
        const float* Bp = (k0 < 512) ? B1 : B2;
        int kk = k0 & 511;
        __syncthreads();
        #pragma unroll
        for (int q = 0; q < 2; ++q){
            int id  = q*256 + tid;
            int row = id >> 3, c4 = (id & 7)*4;
            f32x4 va = *(const f32x4*)&Ap[(size_t)(bm*64+row)*512 + kk + c4];
            f32x4 vb = *(const f32x4*)&Bp[(size_t)(bn*64+row)*512 + kk + c4];
            bf16x4 vah, val_, vbh, vbl;
            #pragma unroll
            for (int j=0;j<4;++j){
                bf16 ha = (bf16)va[j]; vah[j]=ha; val_[j]=(bf16)(va[j]-(float)ha);
                bf16 hb = (bf16)vb[j]; vbh[j]=hb; vbl[j]=(bf16)(vb[j]-(float)hb);
            }
            *(bf16x4*)&Ah[row][c4] = vah;  *(bf16x4*)&Al[row][c4] = val_;
            *(bf16x4*)&Bh[row][c4] = vbh;  *(bf16x4*)&Bl[row][c4] = vbl;
        }
        __syncthreads();
        int koff = (l>>4)*8;
        int ar = wm*32 + (l&15);
        int br = wn*32 + (l&15);
        bf16x8 ah[2], al[2], bh[2], bl[2];
        ah[0]=*(const bf16x8*)&Ah[ar][koff];    ah[1]=*(const bf16x8*)&Ah[ar+16][koff];
        al[0]=*(const bf16x8*)&Al[ar][koff];    al[1]=*(const bf16x8*)&Al[ar+16][koff];
        bh[0]=*(const bf16x8*)&Bh[br][koff];    bh[1]=*(const bf16x8*)&Bh[br+16][koff];
        bl[0]=*(const bf16x8*)&Bl[br][koff];    bl[1]=*(const bf16x8*)&Bl[br+16][koff];
        #pragma unroll
        for (int fm=0; fm<2; ++fm)
        #pragma unroll
        for (int fn=0; fn<2; ++fn){
            acc[fm][fn] = __builtin_amdgcn_mfma_f32_16x16x32_bf16(ah[fm], bh[fn], acc[fm][fn],0,0,0);
            acc[fm][fn] = __builtin_amdgcn_mfma_f32_16x16x32_bf16(ah[fm], bl[fn], acc[fm][fn],0,0,0);
            acc[fm][fn] = __builtin_amdgcn_mfma_f32_16x16x32_bf16(al[fm], bh[fn], acc[fm][fn],0,0,0);
        }
    }
    #pragma unroll
    for (int fm=0; fm<2; ++fm)
    #pragma unroll
    for (int fn=0; fn<2; ++fn){
        #pragma unroll
        for (int r=0; r<4; ++r){
            int m = bm*64 + wm*32 + fm*16 + ((l>>4)<<2) + r;
            int n = bn*64 + wn*32 + fn*16 + (l&15);
            float v = acc[fm][fn][r];
            if (ks == 0){
                if (bias1) v += bias1[m];
                if (bias2) v += bias2[m];
            }
            Cz[(size_t)n*ldct + m] = v;
        }
    }
}

// ---- K1b: LSTM pointwise (sums split-K partials) + zeroes a10 for atomics ----
__global__ __launch_bounds__(256) void lstm_pointwise(
    const float* __restrict__ gatesT, const float* __restrict__ c_in,
    float* __restrict__ h_out, float* __restrict__ c_out, float* __restrict__ a10)
{
    int t = blockIdx.x*256 + threadIdx.x;
    int b = t >> 9, hh = t & 511;
    const float* gp = gatesT + (size_t)b*2048 + hh;
    float gi=0.f, gf=0.f, gg=0.f, go=0.f;
    #pragma unroll
    for (int ks=0; ks<4; ++ks){
        const float* p = gp + (size_t)ks*262144;
        gi += p[0]; gf += p[512]; gg += p[1024]; go += p[1536];
    }
    float i = sigmoidf_(gi), f = sigmoidf_(gf), g = tanhf(gg), o = sigmoidf_(go);
    float cn = f*c_in[t] + i*g;
    float hn = o*tanhf(cn);
    h_out[t] = hn;  c_out[t] = cn;
    a10[t] = 0.f;
}

// ---- K3 v5: r5 structure (A full-K in LDS once, barrier-free K-loop,
// B frag-ordered from L2 2-deep) with HALF the wave col-tile: 8 waves x
// (64r x 32c) per block; block covers 256 cols (half), 2 blocks per row
// interleaved in dispatch.  ~80 regs/lane -> 2 blocks/CU resident AND
// 4 waves/SIMD: co-resident block's compute overlaps this block's staging.
__global__ __launch_bounds__(512,4) void attn_main(
    const float* __restrict__ enc, const bf16* __restrict__ W1s,
    const float* __restrict__ w2hp, const float* __restrict__ Vv,
    float* __restrict__ a10)
{
    __shared__ bf16 Alds[64*512];    // 64 KiB, [row][slot^(row&15)] 16B slots
    __shared__ float w2h_s[512];
    __shared__ float V_s[512];
    __shared__ float red[64][8];
    const int tid = threadIdx.x, w = tid>>6, l = tid&63;
    const int lr = l & 15, lk = l >> 4;
    const int half = blockIdx.x & 1, mb = blockIdx.x >> 1;
    const int m0 = mb * 64;
    const int bidx = mb >> 3;                 // batch index
    const int g = half*8 + w;                 // 32-col group (0..15)
    w2h_s[tid] = w2hp[(size_t)bidx*512 + tid] + w2hp[(size_t)65536 + bidx*512 + tid];
    V_s[tid]   = Vv[tid];

    // frag-ordered B base: 64col-group g>>1, half (g&1), lane l
    const bf16* Bbase = W1s + (size_t)(g>>1)*32768 + (size_t)(g&1)*1024 + (size_t)l*8;

    // prefetch first B parity BEFORE staging (L2 overlaps HBM)
    bf16x8 bA[2], bB[2];
    #pragma unroll
    for (int fn=0; fn<2; ++fn) bA[fn] = *(const bf16x8*)(Bbase + fn*512);

    // ---- stage A once: 64 rows x 512 k, fp32 -> bf16, swizzled ----
    #pragma unroll
    for (int it = 0; it < 8; ++it){
        int c   = it*512 + tid;          // 16B-slot id: 64 slots/row
        int row = c >> 6, s = c & 63;
        const f32x4* gp = (const f32x4*)&enc[(size_t)(m0+row)*512 + s*8];
        f32x4 v0 = gp[0], v1 = gp[1];
        bf16x8 hv;
        #pragma unroll
        for (int j=0;j<4;++j){ hv[j]=(bf16)v0[j]; hv[4+j]=(bf16)v1[j]; }
        int slot = s ^ (row & 15);
        *(bf16x8*)((char*)Alds + row*1024 + slot*16) = hv;
    }
    __syncthreads();

    f32x4 acc[4][2] = {};

    #pragma unroll
    for (int kp = 0; kp < 8; ++kp){
        int ki0 = 2*kp, ki1 = 2*kp+1;
        // prefetch odd
        #pragma unroll
        for (int fn=0; fn<2; ++fn) bB[fn] = *(const bf16x8*)(Bbase + fn*512 + (size_t)ki1*2048);
        // even compute
        {
            bf16x8 af[4];
            #pragma unroll
            for (int fm=0; fm<4; ++fm){
                int row = fm*16 + lr;
                int slot = (ki0*4 + lk) ^ (row & 15);
                af[fm] = *(const bf16x8*)((const char*)Alds + row*1024 + slot*16);
            }
            #pragma unroll
            for (int fm=0; fm<4; ++fm)
            #pragma unroll
            for (int fn=0; fn<2; ++fn)
                acc[fm][fn] = __builtin_amdgcn_mfma_f32_16x16x32_bf16(af[fm], bA[fn], acc[fm][fn],0,0,0);
        }
        // prefetch next even
        if (kp < 7){
            #pragma unroll
            for (int fn=0; fn<2; ++fn) bA[fn] = *(const bf16x8*)(Bbase + fn*512 + (size_t)(ki0+2)*2048);
        }
        // odd compute
        {
            bf16x8 af[4];
            #pragma unroll
            for (int fm=0; fm<4; ++fm){
                int row = fm*16 + lr;
                int slot = (ki1*4 + lk) ^ (row & 15);
                af[fm] = *(const bf16x8*)((const char*)Alds + row*1024 + slot*16);
            }
            #pragma unroll
            for (int fm=0; fm<4; ++fm)
            #pragma unroll
            for (int fn=0; fn<2; ++fn)
                acc[fm][fn] = __builtin_amdgcn_mfma_f32_16x16x32_bf16(af[fm], bB[fn], acc[fm][fn],0,0,0);
        }
    }

    // ---- epilogue: partial over this 32-col group: sum_o tanh(C+w2h[o])*V[o] ----
    #pragma unroll
    for (int fm=0; fm<4; ++fm){
        float asum[4] = {0.f,0.f,0.f,0.f};
        #pragma unroll
        for (int fn=0; fn<2; ++fn){
            int o = g*32 + fn*16 + lr;
            float wv = w2h_s[o], vv = V_s[o];
            #pragma unroll
            for (int r=0;r<4;++r)
                asum[r] += fast_tanh(acc[fm][fn][r] + wv) * vv;
        }
        #pragma unroll
        for (int off=1; off<16; off<<=1){
            #pragma unroll
            for (int r=0;r<4;++r) asum[r] += __shfl_xor(asum[r], off, 64);
        }
        if (lr == 0){
            #pragma unroll
            for (int r=0;r<4;++r) red[fm*16 + lk*4 + r][w] = asum[r];
        }
    }
    __syncthreads();
    if (tid < 64){
        float a = 0.f;
        #pragma unroll
        for (int q=0;q<8;++q) a += red[tid][q];
        atomicAdd(&a10[m0 + tid], a);
    }
}

// ---- K4: masked softmax over S=512 per row (applies 10*tanh to the
// atomically-assembled raw sum) ----
__global__ __launch_bounds__(512) void softmax_k(
    const float* __restrict__ a10, const float* __restrict__ mask,
    float* __restrict__ out)
{
    int b = blockIdx.x, tid = threadIdx.x;
    __shared__ float sred[8];
    float v = 10.0f*fast_tanh(a10[(size_t)b*512 + tid]) + logf(mask[(size_t)b*512 + tid]);
    float m = v;
    #pragma unroll
    for (int off=1; off<64; off<<=1) m = fmaxf(m, __shfl_xor(m, off, 64));
    if ((tid&63)==0) sred[tid>>6] = m;
    __syncthreads();
    float mt = sred[0];
    #pragma unroll
    for (int i=1;i<8;++i) mt = fmaxf(mt, sred[i]);
    float e = expf(v - mt);
    float s = e;
    #pragma unroll
    for (int off=1; off<64; off<<=1) s += __shfl_xor(s, off, 64);
    __syncthreads();
    if ((tid&63)==0) sred[tid>>6] = s;
    __syncthreads();
    float st = 0.f;
    #pragma unroll
    for (int i=0;i<8;++i) st += sred[i];
    out[(size_t)b*512 + tid] = e / st;
}

extern "C" void kernel_launch(void* const* d_in, const int* in_sizes, int n_in,
                              void* d_out, int out_size, void* d_ws, size_t ws_size,
                              hipStream_t stream)
{
    const float* x    = (const float*)d_in[0];
    const float* h    = (const float*)d_in[1];
    const float* c    = (const float*)d_in[2];
    const float* enc  = (const float*)d_in[3];
    const float* mask = (const float*)d_in[4];
    const float* W1   = (const float*)d_in[5];
    const float* W2   = (const float*)d_in[6];
    const float* b2   = (const float*)d_in[7];
    const float* V    = (const float*)d_in[8];
    const float* Wih  = (const float*)d_in[9];
    const float* Whh  = (const float*)d_in[10];
    const float* bih  = (const float*)d_in[11];
    const float* bhh  = (const float*)d_in[12];

    float* out_policy = (float*)d_out;
    float* out_h = out_policy + MS;
    float* out_c = out_policy + 2*MS;

    float* ws_f   = (float*)d_ws;
    float* gatesT = ws_f;                    // 4 x 262144 f32 (split-K partials, [b][j])
    float* w2hp   = ws_f + 1048576;          // 2 x  65536 f32 (split-K partials, [b][o])
    float* a10    = ws_f + 1179648;          //      65536 f32 (atomic accumulator)
    bf16*  W1s    = (bf16*)(ws_f + 1245184); //     262144 bf16 (fragment-ordered)

    cvt_w1_frag<<<128, 256, 0, stream>>>(W1, W1s);
    gemm_split<<<dim3(32,2,4), 256, 0, stream>>>(Wih, Whh, x, h, bih, bhh, gatesT, 128, 256, 2048);
    lstm_pointwise<<<256, 256, 0, stream>>>(gatesT, c, out_h, out_c, a10);
    gemm_split<<<dim3(8,2,2), 256, 0, stream>>>(W2, nullptr, out_h, nullptr, b2, nullptr, w2hp, 128, 256, 512);
    attn_main<<<2048, 512, 0, stream>>>(enc, W1s, w2hp, V, a10);
    softmax_k<<<128, 512, 0, stream>>>(a10, mask, out_policy);
}

// Round 12
// 98.267 us; speedup vs baseline: 7.3112x; 1.0903x over previous
//
#include <hip/hip_runtime.h>
#include <hip/hip_bf16.h>
#include <math.h>

typedef __bf16 bf16;
typedef __bf16 bf16x4 __attribute__((ext_vector_type(4)));
typedef __bf16 bf16x8 __attribute__((ext_vector_type(8)));
typedef float  f32x4  __attribute__((ext_vector_type(4)));

#define HD 512
#define NB 128
#define NS 512
#define MS (NB*NS)   // 65536

__device__ __forceinline__ float sigmoidf_(float x){ return 1.0f/(1.0f+expf(-x)); }

__device__ __forceinline__ float fast_tanh(float x){
    float ax = fabsf(x);
    float e  = __expf(-2.0f*ax);
    float t  = (1.0f - e) * __builtin_amdgcn_rcpf(1.0f + e);
    return copysignf(t, x);
}

// ---- K0: W1 (512x512 fp32 [o][h]) -> bf16 MFMA B-fragment order.
// Frag F = (g64*16 + ki)*4 + fnl ; lane l holds W1[(g64*4+fnl)*16+(l&15)][ki*32+(l>>4)*8+j]
// at W1s[F*512 + l*8 + j].
__global__ __launch_bounds__(256) void cvt_w1_frag(const float* __restrict__ W1, bf16* __restrict__ W1s){
    int F = blockIdx.x*4 + (threadIdx.x>>6);
    int l = threadIdx.x & 63;
    int fnl = F & 3, ki = (F>>2) & 15, g = F>>6;
    int row = (g*4 + fnl)*16 + (l & 15);
    int kk  = ki*32 + (l >> 4)*8;
    const f32x4* gp = (const f32x4*)&W1[(size_t)row*512 + kk];
    f32x4 v0 = gp[0], v1 = gp[1];
    bf16x8 hv;
    #pragma unroll
    for (int j=0;j<4;++j){ hv[j]=(bf16)v0[j]; hv[4+j]=(bf16)v1[j]; }
    *(bf16x8*)&W1s[(size_t)F*512 + (size_t)l*8] = hv;
}

// ---- K1/K2: small GEMM, 3-term bf16 split, split-K, transposed output ----
__global__ __launch_bounds__(256) void gemm_split(
    const float* __restrict__ A1, const float* __restrict__ A2,
    const float* __restrict__ B1, const float* __restrict__ B2,
    const float* __restrict__ bias1, const float* __restrict__ bias2,
    float* __restrict__ C, int N, int ksize, int ldct)
{
    __shared__ bf16 Ah[64][32], Al[64][32], Bh[64][32], Bl[64][32];
    int tid = threadIdx.x;
    int bm = blockIdx.x, bn = blockIdx.y, ks = blockIdx.z;
    int kfrom = ks*ksize, kend = kfrom + ksize;
    float* Cz = C + (size_t)ks * N * ldct;
    int w = tid>>6, l = tid&63;
    int wm = w>>1, wn = w&1;
    f32x4 acc[2][2] = {};
    for (int k0 = kfrom; k0 < kend; k0 += 32){
        const float* Ap = (k0 < 512) ? A1 : A2;
        const float* Bp = (k0 < 512) ? B1 : B2;
        int kk = k0 & 511;
        __syncthreads();
        #pragma unroll
        for (int q = 0; q < 2; ++q){
            int id  = q*256 + tid;
            int row = id >> 3, c4 = (id & 7)*4;
            f32x4 va = *(const f32x4*)&Ap[(size_t)(bm*64+row)*512 + kk + c4];
            f32x4 vb = *(const f32x4*)&Bp[(size_t)(bn*64+row)*512 + kk + c4];
            bf16x4 vah, val_, vbh, vbl;
            #pragma unroll
            for (int j=0;j<4;++j){
                bf16 ha = (bf16)va[j]; vah[j]=ha; val_[j]=(bf16)(va[j]-(float)ha);
                bf16 hb = (bf16)vb[j]; vbh[j]=hb; vbl[j]=(bf16)(vb[j]-(float)hb);
            }
            *(bf16x4*)&Ah[row][c4] = vah;  *(bf16x4*)&Al[row][c4] = val_;
            *(bf16x4*)&Bh[row][c4] = vbh;  *(bf16x4*)&Bl[row][c4] = vbl;
        }
        __syncthreads();
        int koff = (l>>4)*8;
        int ar = wm*32 + (l&15);
        int br = wn*32 + (l&15);
        bf16x8 ah[2], al[2], bh[2], bl[2];
        ah[0]=*(const bf16x8*)&Ah[ar][koff];    ah[1]=*(const bf16x8*)&Ah[ar+16][koff];
        al[0]=*(const bf16x8*)&Al[ar][koff];    al[1]=*(const bf16x8*)&Al[ar+16][koff];
        bh[0]=*(const bf16x8*)&Bh[br][koff];    bh[1]=*(const bf16x8*)&Bh[br+16][koff];
        bl[0]=*(const bf16x8*)&Bl[br][koff];    bl[1]=*(const bf16x8*)&Bl[br+16][koff];
        #pragma unroll
        for (int fm=0; fm<2; ++fm)
        #pragma unroll
        for (int fn=0; fn<2; ++fn){
            acc[fm][fn] = __builtin_amdgcn_mfma_f32_16x16x32_bf16(ah[fm], bh[fn], acc[fm][fn],0,0,0);
            acc[fm][fn] = __builtin_amdgcn_mfma_f32_16x16x32_bf16(ah[fm], bl[fn], acc[fm][fn],0,0,0);
            acc[fm][fn] = __builtin_amdgcn_mfma_f32_16x16x32_bf16(al[fm], bh[fn], acc[fm][fn],0,0,0);
        }
    }
    #pragma unroll
    for (int fm=0; fm<2; ++fm)
    #pragma unroll
    for (int fn=0; fn<2; ++fn){
        #pragma unroll
        for (int r=0; r<4; ++r){
            int m = bm*64 + wm*32 + fm*16 + ((l>>4)<<2) + r;
            int n = bn*64 + wn*32 + fn*16 + (l&15);
            float v = acc[fm][fn][r];
            if (ks == 0){
                if (bias1) v += bias1[m];
                if (bias2) v += bias2[m];
            }
            Cz[(size_t)n*ldct + m] = v;
        }
    }
}

// ---- K1b: LSTM pointwise (sums 4 split-K partials, transposed layout) ----
__global__ __launch_bounds__(256) void lstm_pointwise(
    const float* __restrict__ gatesT, const float* __restrict__ c_in,
    float* __restrict__ h_out, float* __restrict__ c_out)
{
    int t = blockIdx.x*256 + threadIdx.x;
    int b = t >> 9, hh = t & 511;
    const float* gp = gatesT + (size_t)b*2048 + hh;
    float gi=0.f, gf=0.f, gg=0.f, go=0.f;
    #pragma unroll
    for (int ks=0; ks<4; ++ks){
        const float* p = gp + (size_t)ks*262144;
        gi += p[0]; gf += p[512]; gg += p[1024]; go += p[1536];
    }
    float i = sigmoidf_(gi), f = sigmoidf_(gf), g = tanhf(gg), o = sigmoidf_(go);
    float cn = f*c_in[t] + i*g;
    float hn = o*tanhf(cn);
    h_out[t] = hn;  c_out[t] = cn;
}

// ---- K3 v6: r5 geometry (BM=64, BN=512, 8 waves x 64r x 64c, A full-K in
// LDS once, barrier-free K-loop, B frag-ordered 2-deep from L2) with
// NON-TEMPORAL enc staging loads: enc has zero reuse here, and keeping the
// 134 MB enc stream out of L2 keeps the 512 KB W1s image L2-resident --
// B' was ~60 us at L3 bandwidth (r7 ablation algebra), should drop to ~16.
__global__ __launch_bounds__(512,4) void attn_main(
    const float* __restrict__ enc, const bf16* __restrict__ W1s,
    const float* __restrict__ w2hp, const float* __restrict__ Vv,
    float* __restrict__ a_out)
{
    __shared__ bf16 Alds[64*512];    // 64 KiB, [row][slot^(row&15)] 16B slots
    __shared__ float w2h_s[512];
    __shared__ float V_s[512];
    __shared__ float red[64][8];
    const int tid = threadIdx.x, w = tid>>6, l = tid&63;
    const int lr = l & 15, lk = l >> 4;
    const int m0 = blockIdx.x * 64;
    const int bidx = blockIdx.x >> 3;         // batch index
    w2h_s[tid] = w2hp[(size_t)bidx*512 + tid] + w2hp[(size_t)65536 + bidx*512 + tid];
    V_s[tid]   = Vv[tid];

    // frag-ordered B base for wave w (64 cols): + fn*512 + ki*2048
    const bf16* Bbase = W1s + (size_t)w*32768 + (size_t)l*8;

    // prefetch first B parity BEFORE staging (L2 overlaps HBM)
    bf16x8 bA[4], bB[4];
    #pragma unroll
    for (int fn=0; fn<4; ++fn) bA[fn] = *(const bf16x8*)(Bbase + fn*512);

    // ---- stage A once: 64 rows x 512 k, fp32 -> bf16, swizzled, NT loads ----
    #pragma unroll
    for (int it = 0; it < 8; ++it){
        int c   = it*512 + tid;          // 16B-slot id: 64 slots/row
        int row = c >> 6, s = c & 63;
        const f32x4* gp = (const f32x4*)&enc[(size_t)(m0+row)*512 + s*8];
        f32x4 v0 = __builtin_nontemporal_load(gp);
        f32x4 v1 = __builtin_nontemporal_load(gp+1);
        bf16x8 hv;
        #pragma unroll
        for (int j=0;j<4;++j){ hv[j]=(bf16)v0[j]; hv[4+j]=(bf16)v1[j]; }
        int slot = s ^ (row & 15);
        *(bf16x8*)((char*)Alds + row*1024 + slot*16) = hv;
    }
    __syncthreads();

    f32x4 acc[4][4] = {};

    #pragma unroll
    for (int kp = 0; kp < 8; ++kp){
        int ki0 = 2*kp, ki1 = 2*kp+1;
        // prefetch odd
        #pragma unroll
        for (int fn=0; fn<4; ++fn) bB[fn] = *(const bf16x8*)(Bbase + fn*512 + (size_t)ki1*2048);
        // even compute
        {
            bf16x8 af[4];
            #pragma unroll
            for (int fm=0; fm<4; ++fm){
                int row = fm*16 + lr;
                int slot = (ki0*4 + lk) ^ (row & 15);
                af[fm] = *(const bf16x8*)((const char*)Alds + row*1024 + slot*16);
            }
            #pragma unroll
            for (int fm=0; fm<4; ++fm)
            #pragma unroll
            for (int fn=0; fn<4; ++fn)
                acc[fm][fn] = __builtin_amdgcn_mfma_f32_16x16x32_bf16(af[fm], bA[fn], acc[fm][fn],0,0,0);
        }
        // prefetch next even
        if (kp < 7){
            #pragma unroll
            for (int fn=0; fn<4; ++fn) bA[fn] = *(const bf16x8*)(Bbase + fn*512 + (size_t)(ki0+2)*2048);
        }
        // odd compute
        {
            bf16x8 af[4];
            #pragma unroll
            for (int fm=0; fm<4; ++fm){
                int row = fm*16 + lr;
                int slot = (ki1*4 + lk) ^ (row & 15);
                af[fm] = *(const bf16x8*)((const char*)Alds + row*1024 + slot*16);
            }
            #pragma unroll
            for (int fm=0; fm<4; ++fm)
            #pragma unroll
            for (int fn=0; fn<4; ++fn)
                acc[fm][fn] = __builtin_amdgcn_mfma_f32_16x16x32_bf16(af[fm], bB[fn], acc[fm][fn],0,0,0);
        }
    }

    // ---- epilogue: per row, sum_o tanh(C+w2h[o])*V[o] ----
    #pragma unroll
    for (int fm=0; fm<4; ++fm){
        float asum[4] = {0.f,0.f,0.f,0.f};
        #pragma unroll
        for (int fn=0; fn<4; ++fn){
            int o = w*64 + fn*16 + lr;
            float wv = w2h_s[o], vv = V_s[o];
            #pragma unroll
            for (int r=0;r<4;++r)
                asum[r] += fast_tanh(acc[fm][fn][r] + wv) * vv;
        }
        #pragma unroll
        for (int off=1; off<16; off<<=1){
            #pragma unroll
            for (int r=0;r<4;++r) asum[r] += __shfl_xor(asum[r], off, 64);
        }
        if (lr == 0){
            #pragma unroll
            for (int r=0;r<4;++r) red[fm*16 + lk*4 + r][w] = asum[r];
        }
    }
    __syncthreads();
    if (tid < 64){
        float a = 0.f;
        #pragma unroll
        for (int q=0;q<8;++q) a += red[tid][q];
        a_out[m0 + tid] = 10.0f * fast_tanh(a);
    }
}

// ---- K4: masked softmax over S=512 per row (a10 already holds 10*tanh) ----
__global__ __launch_bounds__(512) void softmax_k(
    const float* __restrict__ a10, const float* __restrict__ mask,
    float* __restrict__ out)
{
    int b = blockIdx.x, tid = threadIdx.x;
    __shared__ float sred[8];
    float v = a10[(size_t)b*512 + tid] + logf(mask[(size_t)b*512 + tid]);
    float m = v;
    #pragma unroll
    for (int off=1; off<64; off<<=1) m = fmaxf(m, __shfl_xor(m, off, 64));
    if ((tid&63)==0) sred[tid>>6] = m;
    __syncthreads();
    float mt = sred[0];
    #pragma unroll
    for (int i=1;i<8;++i) mt = fmaxf(mt, sred[i]);
    float e = expf(v - mt);
    float s = e;
    #pragma unroll
    for (int off=1; off<64; off<<=1) s += __shfl_xor(s, off, 64);
    __syncthreads();
    if ((tid&63)==0) sred[tid>>6] = s;
    __syncthreads();
    float st = 0.f;
    #pragma unroll
    for (int i=0;i<8;++i) st += sred[i];
    out[(size_t)b*512 + tid] = e / st;
}

extern "C" void kernel_launch(void* const* d_in, const int* in_sizes, int n_in,
                              void* d_out, int out_size, void* d_ws, size_t ws_size,
                              hipStream_t stream)
{
    const float* x    = (const float*)d_in[0];
    const float* h    = (const float*)d_in[1];
    const float* c    = (const float*)d_in[2];
    const float* enc  = (const float*)d_in[3];
    const float* mask = (const float*)d_in[4];
    const float* W1   = (const float*)d_in[5];
    const float* W2   = (const float*)d_in[6];
    const float* b2   = (const float*)d_in[7];
    const float* V    = (const float*)d_in[8];
    const float* Wih  = (const float*)d_in[9];
    const float* Whh  = (const float*)d_in[10];
    const float* bih  = (const float*)d_in[11];
    const float* bhh  = (const float*)d_in[12];

    float* out_policy = (float*)d_out;
    float* out_h = out_policy + MS;
    float* out_c = out_policy + 2*MS;

    float* ws_f   = (float*)d_ws;
    float* gatesT = ws_f;                    // 4 x 262144 f32 (split-K partials, [b][j])
    float* w2hp   = ws_f + 1048576;          // 2 x  65536 f32 (split-K partials, [b][o])
    float* a10    = ws_f + 1179648;          //      65536 f32
    bf16*  W1s    = (bf16*)(ws_f + 1245184); //     262144 bf16 (fragment-ordered)

    cvt_w1_frag<<<128, 256, 0, stream>>>(W1, W1s);
    gemm_split<<<dim3(32,2,4), 256, 0, stream>>>(Wih, Whh, x, h, bih, bhh, gatesT, 128, 256, 2048);
    lstm_pointwise<<<256, 256, 0, stream>>>(gatesT, c, out_h, out_c);
    gemm_split<<<dim3(8,2,2), 256, 0, stream>>>(W2, nullptr, out_h, nullptr, b2, nullptr, w2hp, 128, 256, 512);
    attn_main<<<1024, 512, 0, stream>>>(enc, W1s, w2hp, V, a10);
    softmax_k<<<128, 512, 0, stream>>>(a10, mask, out_policy);
}